// Round 6
// baseline (1154.383 us; speedup 1.0000x reference)
//
#include <hip/hip_runtime.h>

// ConvSNN forward, T=16, B=128. conv2/conv3/fc1 via MFMA bf16 with TRIPLE-split
// weights (hi+mid+lo bf16 ~= fp32 to ~2^-27 rel); activations are pooled spikes
// in {0,.25,.5,.75,1}, exact in bf16. LIF/LI state fp32. No memset: t==0 kernels
// skip the state read (v=i=0) and write fresh.
// LIF: vd = v + 0.1*(i - v); z = (vd>th); v' = z?0:vd; i' = 0.8*i + inp

typedef __attribute__((ext_vector_type(8))) short bf16x8;
typedef __attribute__((ext_vector_type(4))) float f32x4;

__device__ __forceinline__ unsigned short f2bf(float f) {
  unsigned int u = __float_as_uint(f);
  return (unsigned short)((u + 0x7fffu + ((u >> 16) & 1u)) >> 16);
}
__device__ __forceinline__ float bf2f(unsigned short h) {
  return __uint_as_float(((unsigned int)h) << 16);
}
__device__ __forceinline__ unsigned short split3(float wv, int sp) {
  unsigned short hi = f2bf(wv);
  float r1 = wv - bf2f(hi);
  unsigned short mid = f2bf(r1);
  if (sp == 0) return hi;
  if (sp == 1) return mid;
  return f2bf(r1 - bf2f(mid));
}
__device__ __forceinline__ float lif1(float inp, float vth, float& v, float& i) {
  float vd = fmaf(0.1f, i - v, v);
  float z = (vd > vth) ? 1.0f : 0.0f;
  v = (vd > vth) ? 0.0f : vd;
  i = fmaf(0.8f, i, inp);
  return z;
}
__device__ __forceinline__ f32x4 mfma16(bf16x8 a, bf16x8 b, f32x4 c) {
  return __builtin_amdgcn_mfma_f32_16x16x32_bf16(a, b, c, 0, 0, 0);
}

// ---------- one-time weight split+pack into B-fragment order ----------
// conv2 layout: [ocg 2][sp 3][dydx 9][g 4][ocl 32][j 8]  (ic = 8g+j); 55296
__global__ __launch_bounds__(256) void k_pack2(const float* __restrict__ wc2,
                                               unsigned short* __restrict__ wpk) {
  int idx = blockIdx.x * 256 + threadIdx.x;
  if (idx >= 55296) return;
  int j = idx & 7, ocl = (idx >> 3) & 31, g = (idx >> 8) & 3;
  int r = idx >> 10;                        // 0..53
  int dydx = r % 9; int q = r / 9;          // 0..5
  int sp = q % 3, ocg = q / 3;
  int oc = ocg * 32 + ocl, ic = g * 8 + j;
  wpk[idx] = split3(wc2[(oc * 32 + ic) * 9 + dydx], sp);
}
// conv3 layout: [ocg 8][ics 2][sp 3][dydx 9][g 4][ocl 16][j 8]; 442368
__global__ __launch_bounds__(256) void k_pack3(const float* __restrict__ wc3,
                                               unsigned short* __restrict__ wpk) {
  int idx = blockIdx.x * 256 + threadIdx.x;
  if (idx >= 442368) return;
  int j = idx & 7, ocl = (idx >> 3) & 15, g = (idx >> 7) & 3;
  int r = idx >> 9;
  int dydx = r % 9; int q = r / 9;
  int sp = q % 3; int q2 = q / 3;
  int ics = q2 & 1, ocg = q2 >> 1;
  int oc = ocg * 16 + ocl, ic = ics * 32 + g * 8 + j;
  wpk[idx] = split3(wc3[(oc * 64 + ic) * 9 + dydx], sp);
}

// ---------- conv1 (3->32) fp32 + LIF(0.25) + pool -> z1bf (B,16,16,32) bf16 ----------
__global__ __launch_bounds__(256) void k_conv1(const float* __restrict__ x,
    const float* __restrict__ wc, float4* __restrict__ s1v, float4* __restrict__ s1i,
    unsigned short* __restrict__ z1bf, int first)
{
  const int bid = blockIdx.x;
  const int g = bid & 1, h = (bid >> 1) & 1, b = bid >> 2;
  const int tid = threadIdx.x;
  __shared__ float xs[3][18][34];
  __shared__ float wl[16][27];
  for (int i = tid; i < 432; i += 256) wl[i / 27][i % 27] = wc[g * 432 + i];
  for (int i = tid; i < 3 * 18 * 34; i += 256) {
    int c = i / 612, rr = i % 612;
    int row = rr / 34, col = rr % 34;
    int gy = h * 16 + row - 1, gx = col - 1;
    float v = 0.f;
    if (gy >= 0 && gy < 32 && gx >= 0 && gx < 32)
      v = x[((b * 3 + c) * 32 + gy) * 32 + gx];
    xs[c][row][col] = v;
  }
  __syncthreads();
  const int site = tid >> 1, sub = tid & 1;
  const int ph = site >> 4, pw = site & 15;
  float p[3][4][4];
#pragma unroll
  for (int c = 0; c < 3; ++c)
#pragma unroll
    for (int r = 0; r < 4; ++r)
#pragma unroll
      for (int cc = 0; cc < 4; ++cc)
        p[c][r][cc] = xs[c][2 * ph + r][2 * pw + cc];
  unsigned short zout[8];
  const int py = h * 8 + ph;
#pragma unroll
  for (int jj = 0; jj < 8; ++jj) {
    const float* wv = &wl[sub * 8 + jj][0];
    float s00 = 0, s01 = 0, s10 = 0, s11 = 0;
#pragma unroll
    for (int c = 0; c < 3; ++c)
#pragma unroll
      for (int kh = 0; kh < 3; ++kh)
#pragma unroll
        for (int kw = 0; kw < 3; ++kw) {
          float wvv = wv[(c * 3 + kh) * 3 + kw];
          s00 = fmaf(p[c][kh][kw],     wvv, s00);
          s01 = fmaf(p[c][kh][kw+1],   wvv, s01);
          s10 = fmaf(p[c][kh+1][kw],   wvv, s10);
          s11 = fmaf(p[c][kh+1][kw+1], wvv, s11);
        }
    int oc = g * 16 + sub * 8 + jj;
    int sidx = ((b * 32 + oc) * 16 + py) * 16 + pw;
    float4 v4, i4;
    if (first) { v4 = {0.f,0.f,0.f,0.f}; i4 = {0.f,0.f,0.f,0.f}; }
    else       { v4 = s1v[sidx]; i4 = s1i[sidx]; }
    float z0 = lif1(s00, 0.25f, v4.x, i4.x);
    float z1 = lif1(s01, 0.25f, v4.y, i4.y);
    float z2 = lif1(s10, 0.25f, v4.z, i4.z);
    float z3 = lif1(s11, 0.25f, v4.w, i4.w);
    s1v[sidx] = v4; s1i[sidx] = i4;
    zout[jj] = f2bf(0.25f * (z0 + z1 + z2 + z3));
  }
  *(uint4*)&z1bf[((b * 16 + py) * 16 + pw) * 32 + g * 16 + sub * 8] = *(uint4*)zout;
}

// ---------- conv2 (32->64) MFMA + LIF(0.2) + pool -> z2bf (B,8,8,64) bf16 ----------
// grid 512 = ocg(2) x q(4 row-quads) x bg(64: 2 imgs); 512 thr = 8 waves.
// All 3 weight splits staged once (55KB); zpl aliased onto dead wl region.
__global__ __launch_bounds__(512) void k_conv2(const unsigned short* __restrict__ z1bf,
    const unsigned short* __restrict__ wpk, float* __restrict__ s2v, float* __restrict__ s2i,
    unsigned short* __restrict__ z2bf, int first)
{
  const int bid = blockIdx.x;
  const int ocg = bid & 1, q = (bid >> 1) & 3, bg = bid >> 3;
  const int b0 = bg * 2;
  const int tid = threadIdx.x;
  __shared__ __align__(16) unsigned short wl[27648];          // [sp3][dydx9][g4][ocl32][j8]
  __shared__ __align__(16) unsigned short img[2][6][18][40];
  {
    const uint4* wsrc = (const uint4*)(wpk + ocg * 27648);
    for (int i = tid; i < 3456; i += 512) ((uint4*)wl)[i] = wsrc[i];
  }
  if (tid < 216) {
    int bl = tid / 108, rr = tid % 108;
    int row = rr / 18, col = rr % 18;
    int gy = q * 4 - 1 + row, gx = col - 1;
    uint4* d = (uint4*)&img[bl][row][col][0];
    uint4 zz = {0, 0, 0, 0};
    if (gy >= 0 && gy < 16 && gx >= 0 && gx < 16) {
      const uint4* s = (const uint4*)(z1bf + (((b0 + bl) * 16 + gy) * 16 + gx) * 32);
      d[0] = s[0]; d[1] = s[1]; d[2] = s[2]; d[3] = s[3]; d[4] = zz;
    } else { d[0] = zz; d[1] = zz; d[2] = zz; d[3] = zz; d[4] = zz; }
  }
  __syncthreads();
  const int w = tid >> 6, l = tid & 63;
  const int bl = w >> 2, wlr = w & 3;
  const int lg = l >> 4, ll = l & 15;
  f32x4 acc[2] = {};
  for (int sp = 0; sp < 3; ++sp) {
    for (int s9 = 0; s9 < 9; ++s9) {
      const int dy = s9 / 3, dx = s9 % 3;
      bf16x8 a = *(const bf16x8*)&img[bl][wlr + dy][ll + dx][8 * lg];
#pragma unroll
      for (int tl = 0; tl < 2; ++tl) {
        bf16x8 bw = *(const bf16x8*)&wl[((sp * 9 + s9) * 4 + lg) * 256 + (tl * 16 + ll) * 8];
        acc[tl] = mfma16(a, bw, acc[tl]);
      }
    }
  }
  __syncthreads();                       // all MFMA reads done; wl dead
  unsigned short* zpl = wl;              // [8][16][32]
  const int y = q * 4 + wlr;
  const int b = b0 + bl;
#pragma unroll
  for (int tl = 0; tl < 2; ++tl) {
#pragma unroll
    for (int r = 0; r < 4; ++r) {
      int xx = 4 * lg + r;
      int ocl = tl * 16 + ll;
      int idx = ((b * 16 + y) * 16 + xx) * 64 + ocg * 32 + ocl;
      float v, ii;
      if (first) { v = 0.f; ii = 0.f; } else { v = s2v[idx]; ii = s2i[idx]; }
      float z = lif1(acc[tl][r], 0.2f, v, ii);
      s2v[idx] = v; s2i[idx] = ii;
      zpl[(w * 16 + xx) * 32 + ocl] = f2bf(z);
    }
  }
  __syncthreads();
  {
    int e = tid;
    int bl2 = e >> 8, m = (e >> 7) & 1, pp = (e >> 4) & 7, oc2 = (e & 15) * 2;
    int w0 = bl2 * 4 + 2 * m;
    float s0 = bf2f(zpl[(w0*16 + 2*pp)*32 + oc2])     + bf2f(zpl[(w0*16 + 2*pp+1)*32 + oc2]) +
               bf2f(zpl[((w0+1)*16 + 2*pp)*32 + oc2]) + bf2f(zpl[((w0+1)*16 + 2*pp+1)*32 + oc2]);
    float s1 = bf2f(zpl[(w0*16 + 2*pp)*32 + oc2+1])     + bf2f(zpl[(w0*16 + 2*pp+1)*32 + oc2+1]) +
               bf2f(zpl[((w0+1)*16 + 2*pp)*32 + oc2+1]) + bf2f(zpl[((w0+1)*16 + 2*pp+1)*32 + oc2+1]);
    unsigned int pk = (unsigned int)f2bf(0.25f * s0) | ((unsigned int)f2bf(0.25f * s1) << 16);
    *(unsigned int*)&z2bf[((((b0 + bl2) * 8) + q * 2 + m) * 8 + pp) * 64 + ocg * 32 + oc2] = pk;
  }
}

// ---------- conv3 (64->128) MFMA full-K + LIF(0.1) + pool -> z3t (fused c3red) ----------
// grid 512 = ocg(8: 16 oc) x bg(64: 2 imgs); 512 thr = 8 waves (2 img x 4 row-pairs)
__global__ __launch_bounds__(512) void k_conv3(const unsigned short* __restrict__ z2bf,
    const unsigned short* __restrict__ wpk, float* __restrict__ s3v, float* __restrict__ s3i,
    unsigned short* __restrict__ z3t, int first)
{
  const int bid = blockIdx.x;
  const int ocg = bid & 7, bg = bid >> 3;
  const int b0 = bg * 2;
  const int tid = threadIdx.x;
  __shared__ __align__(16) unsigned short wl[13824];       // one ics: [sp3][9][g4][ocl16][j8]
  __shared__ __align__(16) unsigned short img[2][10][12][72]; // 64 ic + 8 pad
  if (tid < 240) {
    int bl = tid / 120, rr = tid % 120;
    int row = rr / 12, col = rr % 12;
    int gy = row - 1, gx = col - 1;
    uint4* d = (uint4*)&img[bl][row][col][0];
    uint4 zz = {0, 0, 0, 0};
    if (gy >= 0 && gy < 8 && gx >= 0 && gx < 8) {
      const uint4* s = (const uint4*)(z2bf + (((b0 + bl) * 8 + gy) * 8 + gx) * 64);
#pragma unroll
      for (int u = 0; u < 8; ++u) d[u] = s[u];
      d[8] = zz;
    } else {
#pragma unroll
      for (int u = 0; u < 9; ++u) d[u] = zz;
    }
  }
  const int w = tid >> 6, l = tid & 63;
  const int bl = w >> 2, q3 = w & 3;
  const int lg = l >> 4, ll = l & 15;
  const int ry = ll >> 3, xi = ll & 7;
  f32x4 acc = {};
  for (int ics = 0; ics < 2; ++ics) {
    if (ics) __syncthreads();            // prior MFMA reads of wl done
    {
      const uint4* wsrc = (const uint4*)(wpk + (ocg * 2 + ics) * 13824);
      for (int i = tid; i < 1728; i += 512) ((uint4*)wl)[i] = wsrc[i];
    }
    __syncthreads();                     // covers img staging on ics==0 too
    for (int sp = 0; sp < 3; ++sp) {
      for (int s9 = 0; s9 < 9; ++s9) {
        const int dy = s9 / 3, dx = s9 % 3;
        bf16x8 a = *(const bf16x8*)&img[bl][2 * q3 + ry + dy][xi + dx][ics * 32 + 8 * lg];
        bf16x8 bw = *(const bf16x8*)&wl[((sp * 9 + s9) * 4 + lg) * 128 + ll * 8];
        acc = mfma16(a, bw, acc);
      }
    }
  }
  __syncthreads();                       // wl dead
  unsigned short* zpl = wl;              // [8 waves][16 px][16 oc]
  const int b = b0 + bl;
#pragma unroll
  for (int r = 0; r < 4; ++r) {
    int px = 4 * lg + r;
    int yy = 2 * q3 + (px >> 3), xx = px & 7;
    int oc = ocg * 16 + ll;
    int si = ((b * 8 + yy) * 8 + xx) * 128 + oc;
    float v, ii;
    if (first) { v = 0.f; ii = 0.f; } else { v = s3v[si]; ii = s3i[si]; }
    float z = lif1(acc[r], 0.1f, v, ii);
    s3v[si] = v; s3i[si] = ii;
    zpl[(w * 16 + px) * 16 + ll] = f2bf(z);
  }
  __syncthreads();
  {
    int e = tid;
    int ocl = e & 15, site = (e >> 4) & 15, bl2 = e >> 8;
    int py = site >> 2, ppx = site & 3;
    int w0 = bl2 * 4 + py;
    float zsum = bf2f(zpl[(w0*16 + 2*ppx)*16 + ocl])   + bf2f(zpl[(w0*16 + 2*ppx+1)*16 + ocl]) +
                 bf2f(zpl[(w0*16 + 8+2*ppx)*16 + ocl]) + bf2f(zpl[(w0*16 + 8+2*ppx+1)*16 + ocl]);
    z3t[(b0 + bl2) * 2048 + (ocg * 16 + ocl) * 16 + py * 4 + ppx] = f2bf(0.25f * zsum);
  }
}

// ---------- fc1 (2048->1024) MFMA, K-split 8 -> P1[8][b 128][n 1024] ----------
__global__ __launch_bounds__(512) void k_fc1(const unsigned short* __restrict__ z3t,
    const float* __restrict__ wf1, float* __restrict__ P1)
{
  const int bid = blockIdx.x;
  const int kb = bid & 7, nb = (bid >> 3) & 31, bb = bid >> 8;
  const int tid = threadIdx.x;
  __shared__ __align__(16) unsigned short slab[16384];  // [64 b][32 grp^swz][8]
  __shared__ __align__(16) unsigned short wl[8192];     // [ks 8][g 4][n 32][8]
  for (int gidx = tid; gidx < 2048; gidx += 512) {
    int row = gidx >> 5, gc = gidx & 31;
    const uint4* s = (const uint4*)(z3t + ((bb * 64 + row) * 2048 + kb * 256 + gc * 8));
    ((uint4*)slab)[row * 32 + (gc ^ (row & 7))] = *s;
  }
  const int w = tid >> 6, l = tid & 63;
  const int lg = l >> 4, ll = l & 15;
  const int bt = w >> 1, nt = w & 1;
  const int arow = bt * 16 + ll;
  f32x4 acc = {};
  for (int sp = 0; sp < 3; ++sp) {
    if (sp) __syncthreads();
    for (int idx = tid; idx < 8192; idx += 512) {
      int n = idx >> 8, k = idx & 255;
      float wv = wf1[(size_t)(nb * 32 + n) * 2048 + kb * 256 + k];
      int ks = k >> 5, g = (k >> 3) & 3, j = k & 7;
      wl[((ks * 4 + g) * 32 + n) * 8 + j] = split3(wv, sp);
    }
    __syncthreads();
#pragma unroll
    for (int ks = 0; ks < 8; ++ks) {
      bf16x8 a = *(const bf16x8*)&slab[(arow * 32 + ((ks * 4 + lg) ^ (arow & 7))) * 8];
      bf16x8 bw = *(const bf16x8*)&wl[((ks * 4 + lg) * 32 + nt * 16 + ll) * 8];
      acc = mfma16(a, bw, acc);
    }
  }
  const int bo = bb * 64 + bt * 16;
#pragma unroll
  for (int r = 0; r < 4; ++r)
    P1[(size_t)kb * 131072 + (bo + 4 * lg + r) * 1024 + nb * 32 + nt * 16 + ll] = acc[r];
}

// ---------- fused: P1 reduce + LIF(0.1) + out layer (1024->10) + LI + running max ----------
// grid 32 x 256 thr: wave per batch row (4 b per block)
__global__ __launch_bounds__(256) void k_out(const float* __restrict__ P1,
    const float* __restrict__ wo, float* __restrict__ s4v, float* __restrict__ s4i,
    float* __restrict__ sov, float* __restrict__ soi, float* __restrict__ out, int first)
{
  const int w = threadIdx.x >> 6, l = threadIdx.x & 63;
  const int b = blockIdx.x * 4 + w;
  float dot[10];
#pragma unroll
  for (int o = 0; o < 10; ++o) dot[o] = 0.f;
  for (int c = 0; c < 16; ++c) {
    const int n = c * 64 + l;
    const int si = b * 1024 + n;
    float a = 0.f;
#pragma unroll
    for (int kb = 0; kb < 8; ++kb) a += P1[(size_t)kb * 131072 + si];
    float v, ii;
    if (first) { v = 0.f; ii = 0.f; } else { v = s4v[si]; ii = s4i[si]; }
    float z = lif1(a, 0.1f, v, ii);
    s4v[si] = v; s4i[si] = ii;
#pragma unroll
    for (int o = 0; o < 10; ++o) dot[o] = fmaf(z, wo[o * 1024 + n], dot[o]);
  }
#pragma unroll
  for (int o = 0; o < 10; ++o)
#pragma unroll
    for (int d = 32; d > 0; d >>= 1) dot[o] += __shfl_down(dot[o], d);
  if (l == 0) {
#pragma unroll
    for (int o = 0; o < 10; ++o) {
      int si = b * 10 + o;
      float v, ii;
      if (first) { v = 0.f; ii = 0.f; } else { v = sov[si]; ii = soi[si]; }
      float vn = fmaf(0.1f, ii - v, v);
      soi[si] = fmaf(0.8f, ii, dot[o]);
      sov[si] = vn;
      float* op = out + b * 10 + o;
      if (first) *op = vn; else *op = fmaxf(*op, vn);
    }
  }
}

extern "C" void kernel_launch(void* const* d_in, const int* in_sizes, int n_in,
                              void* d_out, int out_size, void* d_ws, size_t ws_size,
                              hipStream_t stream)
{
  const float* x   = (const float*)d_in[0];   // (16,128,3,32,32)
  const float* wc1 = (const float*)d_in[1];   // (32,3,3,3)
  const float* wc2 = (const float*)d_in[2];   // (64,32,3,3)
  const float* wc3 = (const float*)d_in[3];   // (128,64,3,3)
  const float* wf1 = (const float*)d_in[4];   // (1024,2048)
  const float* wo  = (const float*)d_in[5];   // (10,1024)
  float* out = (float*)d_out;                 // (128,10)
  char* ws = (char*)d_ws;

  // byte offsets (no zero-init needed: first-step kernels write state fresh)
  float4* s1v = (float4*)(ws + 0);                         // (B,32,16,16) float4 sites
  float4* s1i = (float4*)(ws + 16777216);
  float* s2v  = (float*)(ws + 33554432);                   // (B,16,16,64)
  float* s2i  = (float*)(ws + 41943040);
  float* s3v  = (float*)(ws + 50331648);                   // (B,8,8,128)
  float* s3i  = (float*)(ws + 54525952);
  float* s4v  = (float*)(ws + 58720256);                   // (B,1024)
  float* s4i  = (float*)(ws + 59244544);
  float* sov  = (float*)(ws + 59768832);                   // (B,10)
  float* soi  = (float*)(ws + 59773952);
  unsigned short* z1bf = (unsigned short*)(ws + 59779072); // (B,16,16,32)
  unsigned short* z2bf = (unsigned short*)(ws + 61876224); // (B,8,8,64)
  unsigned short* z3t  = (unsigned short*)(ws + 62924800); // (B,2048)
  float* P1            = (float*)(ws + 63449088);          // 8x131072 floats = 4 MB
  unsigned short* wc2pk = (unsigned short*)(ws + 67643392); // 55296 sh
  unsigned short* wc3pk = (unsigned short*)(ws + 67753984); // 442368 sh
  // end 68,638,720 bytes

  k_pack2<<<216, 256, 0, stream>>>(wc2, wc2pk);
  k_pack3<<<1728, 256, 0, stream>>>(wc3, wc3pk);

  for (int t = 0; t < 16; ++t) {
    const int first = (t == 0) ? 1 : 0;
    const float* xt = x + (size_t)t * 393216;
    k_conv1<<<512, 256, 0, stream>>>(xt, wc1, s1v, s1i, z1bf, first);
    k_conv2<<<512, 512, 0, stream>>>(z1bf, wc2pk, s2v, s2i, z2bf, first);
    k_conv3<<<512, 512, 0, stream>>>(z2bf, wc3pk, s3v, s3i, z3t, first);
    k_fc1 <<<512, 512, 0, stream>>>(z3t, wf1, P1);
    k_out <<<32, 256, 0, stream>>>(P1, wo, s4v, s4i, sov, soi, out, first);
  }
}

// Round 7
// 407.978 us; speedup vs baseline: 2.8295x; 2.8295x over previous
//
#include <hip/hip_runtime.h>

// ConvSNN forward, T=16, B=128. One kernel per LAYER, t-loop inside, LIF state
// in REGISTERS (no global state, no memset). conv2/conv3/fc1 via MFMA bf16 with
// TRIPLE-split weights (hi+mid+lo ~= fp32 to ~2^-27 rel); activations are pooled
// spikes in {0,.25,.5,.75,1}, exact in bf16.
// LIF: vd = v + 0.1*(i - v); z = (vd>th); v' = z?0:vd; i' = 0.8*i + inp

typedef __attribute__((ext_vector_type(8))) short bf16x8;
typedef __attribute__((ext_vector_type(4))) float f32x4;

__device__ __forceinline__ unsigned short f2bf(float f) {
  unsigned int u = __float_as_uint(f);
  return (unsigned short)((u + 0x7fffu + ((u >> 16) & 1u)) >> 16);
}
__device__ __forceinline__ float bf2f(unsigned short h) {
  return __uint_as_float(((unsigned int)h) << 16);
}
__device__ __forceinline__ unsigned short split3(float wv, int sp) {
  unsigned short hi = f2bf(wv);
  float r1 = wv - bf2f(hi);
  unsigned short mid = f2bf(r1);
  if (sp == 0) return hi;
  if (sp == 1) return mid;
  return f2bf(r1 - bf2f(mid));
}
__device__ __forceinline__ float lif1(float inp, float vth, float& v, float& i) {
  float vd = fmaf(0.1f, i - v, v);
  float z = (vd > vth) ? 1.0f : 0.0f;
  v = (vd > vth) ? 0.0f : vd;
  i = fmaf(0.8f, i, inp);
  return z;
}
__device__ __forceinline__ f32x4 mfma16(bf16x8 a, bf16x8 b, f32x4 c) {
  return __builtin_amdgcn_mfma_f32_16x16x32_bf16(a, b, c, 0, 0, 0);
}

// ---------- one-time weight split+pack into B-fragment order ----------
// conv2 layout: [ocg 2][sp 3][dydx 9][g 4][ocl 32][j 8]  (ic = 8g+j); 55296
__global__ __launch_bounds__(256) void k_pack2(const float* __restrict__ wc2,
                                               unsigned short* __restrict__ wpk) {
  int idx = blockIdx.x * 256 + threadIdx.x;
  if (idx >= 55296) return;
  int j = idx & 7, ocl = (idx >> 3) & 31, g = (idx >> 8) & 3;
  int r = idx >> 10;                        // 0..53
  int dydx = r % 9; int q = r / 9;          // 0..5
  int sp = q % 3, ocg = q / 3;
  int oc = ocg * 32 + ocl, ic = g * 8 + j;
  wpk[idx] = split3(wc2[(oc * 32 + ic) * 9 + dydx], sp);
}
// conv3 layout: [ocg 8][ics 2][sp 3][dydx 9][g 4][ocl 16][j 8]; 442368
__global__ __launch_bounds__(256) void k_pack3(const float* __restrict__ wc3,
                                               unsigned short* __restrict__ wpk) {
  int idx = blockIdx.x * 256 + threadIdx.x;
  if (idx >= 442368) return;
  int j = idx & 7, ocl = (idx >> 3) & 15, g = (idx >> 7) & 3;
  int r = idx >> 9;
  int dydx = r % 9; int q = r / 9;
  int sp = q % 3; int q2 = q / 3;
  int ics = q2 & 1, ocg = q2 >> 1;
  int oc = ocg * 16 + ocl, ic = ics * 32 + g * 8 + j;
  wpk[idx] = split3(wc3[(oc * 64 + ic) * 9 + dydx], sp);
}

// ---------- conv1 (3->32) fp32, t-loop, state in regs -> z1bf[t] (B,16,16,32) ----------
// grid 512 = b(128) x h(2) x g(2); 256 thr = 128 pooled sites x 2 sub(8 oc each)
__global__ __launch_bounds__(256) void k_conv1(const float* __restrict__ x,
    const float* __restrict__ wc, unsigned short* __restrict__ z1bf)
{
  const int bid = blockIdx.x;
  const int g = bid & 1, h = (bid >> 1) & 1, b = bid >> 2;
  const int tid = threadIdx.x;
  __shared__ float xs[3][18][34];
  __shared__ float wl[16][27];
  for (int i = tid; i < 432; i += 256) wl[i / 27][i % 27] = wc[g * 432 + i];
  const int site = tid >> 1, sub = tid & 1;
  const int ph = site >> 4, pw = site & 15;
  const int py = h * 8 + ph;
  float vst[8][4], ist[8][4];
#pragma unroll
  for (int jj = 0; jj < 8; ++jj)
#pragma unroll
    for (int r = 0; r < 4; ++r) { vst[jj][r] = 0.f; ist[jj][r] = 0.f; }

  for (int t = 0; t < 16; ++t) {
    __syncthreads();                      // prior-t readers of xs done
    const float* xt = x + (size_t)t * 393216;
    for (int i = tid; i < 3 * 18 * 34; i += 256) {
      int c = i / 612, rr = i % 612;
      int row = rr / 34, col = rr % 34;
      int gy = h * 16 + row - 1, gx = col - 1;
      float v = 0.f;
      if (gy >= 0 && gy < 32 && gx >= 0 && gx < 32)
        v = xt[((b * 3 + c) * 32 + gy) * 32 + gx];
      xs[c][row][col] = v;
    }
    __syncthreads();
    float p[3][4][4];
#pragma unroll
    for (int c = 0; c < 3; ++c)
#pragma unroll
      for (int r = 0; r < 4; ++r)
#pragma unroll
        for (int cc = 0; cc < 4; ++cc)
          p[c][r][cc] = xs[c][2 * ph + r][2 * pw + cc];
    unsigned short zout[8];
#pragma unroll
    for (int jj = 0; jj < 8; ++jj) {
      const float* wv = &wl[sub * 8 + jj][0];
      float s00 = 0, s01 = 0, s10 = 0, s11 = 0;
#pragma unroll
      for (int c = 0; c < 3; ++c)
#pragma unroll
        for (int kh = 0; kh < 3; ++kh)
#pragma unroll
          for (int kw = 0; kw < 3; ++kw) {
            float wvv = wv[(c * 3 + kh) * 3 + kw];
            s00 = fmaf(p[c][kh][kw],     wvv, s00);
            s01 = fmaf(p[c][kh][kw+1],   wvv, s01);
            s10 = fmaf(p[c][kh+1][kw],   wvv, s10);
            s11 = fmaf(p[c][kh+1][kw+1], wvv, s11);
          }
      float z0 = lif1(s00, 0.25f, vst[jj][0], ist[jj][0]);
      float z1 = lif1(s01, 0.25f, vst[jj][1], ist[jj][1]);
      float z2 = lif1(s10, 0.25f, vst[jj][2], ist[jj][2]);
      float z3 = lif1(s11, 0.25f, vst[jj][3], ist[jj][3]);
      zout[jj] = f2bf(0.25f * (z0 + z1 + z2 + z3));
    }
    *(uint4*)&z1bf[(size_t)t * 1048576 + ((b * 16 + py) * 16 + pw) * 32 + g * 16 + sub * 8]
        = *(uint4*)zout;
  }
}

// ---------- conv2 (32->64) MFMA, t-loop, state in regs -> z2bf[t] (B,8,8,64) ----------
// grid 512 = ocg(2) x q(4 row-quads) x bg(64: 2 imgs); 512 thr = 8 waves.
// LDS: wl 55296 + img 17280 + zpl 8192 = 80768 B -> 2 blocks/CU.
__global__ __launch_bounds__(512) void k_conv2(const unsigned short* __restrict__ z1bf,
    const unsigned short* __restrict__ wpk, unsigned short* __restrict__ z2bf)
{
  const int bid = blockIdx.x;
  const int ocg = bid & 1, q = (bid >> 1) & 3, bg = bid >> 3;
  const int b0 = bg * 2;
  const int tid = threadIdx.x;
  __shared__ __align__(16) unsigned short wl[27648];          // [sp3][9][g4][ocl32][j8]
  __shared__ __align__(16) unsigned short img[2][6][18][40];
  __shared__ __align__(16) unsigned short zpl[4096];          // [8 w][16 x][32 oc]
  {
    const uint4* wsrc = (const uint4*)(wpk + ocg * 27648);
    for (int i = tid; i < 3456; i += 512) ((uint4*)wl)[i] = wsrc[i];
  }
  const int w = tid >> 6, l = tid & 63;
  const int bl = w >> 2, wlr = w & 3;
  const int lg = l >> 4, ll = l & 15;
  float vst[2][4], ist[2][4];
#pragma unroll
  for (int tl = 0; tl < 2; ++tl)
#pragma unroll
    for (int r = 0; r < 4; ++r) { vst[tl][r] = 0.f; ist[tl][r] = 0.f; }

  for (int t = 0; t < 16; ++t) {
    __syncthreads();                      // prior-t MFMA img reads + pool zpl reads done
    if (tid < 216) {
      int ibl = tid / 108, rr = tid % 108;
      int row = rr / 18, col = rr % 18;
      int gy = q * 4 - 1 + row, gx = col - 1;
      uint4* d = (uint4*)&img[ibl][row][col][0];
      uint4 zz = {0, 0, 0, 0};
      if (gy >= 0 && gy < 16 && gx >= 0 && gx < 16) {
        const uint4* s = (const uint4*)(z1bf + (size_t)t * 1048576 +
                                        (((b0 + ibl) * 16 + gy) * 16 + gx) * 32);
        d[0] = s[0]; d[1] = s[1]; d[2] = s[2]; d[3] = s[3]; d[4] = zz;
      } else { d[0] = zz; d[1] = zz; d[2] = zz; d[3] = zz; d[4] = zz; }
    }
    __syncthreads();
    f32x4 acc[2] = {};
    for (int sp = 0; sp < 3; ++sp) {
      for (int s9 = 0; s9 < 9; ++s9) {
        const int dy = s9 / 3, dx = s9 % 3;
        bf16x8 a = *(const bf16x8*)&img[bl][wlr + dy][ll + dx][8 * lg];
#pragma unroll
        for (int tl = 0; tl < 2; ++tl) {
          bf16x8 bw = *(const bf16x8*)&wl[((sp * 9 + s9) * 4 + lg) * 256 + (tl * 16 + ll) * 8];
          acc[tl] = mfma16(a, bw, acc[tl]);
        }
      }
    }
#pragma unroll
    for (int tl = 0; tl < 2; ++tl) {
#pragma unroll
      for (int r = 0; r < 4; ++r) {
        int xx = 4 * lg + r;
        float z = lif1(acc[tl][r], 0.2f, vst[tl][r], ist[tl][r]);
        zpl[(w * 16 + xx) * 32 + tl * 16 + ll] = f2bf(z);
      }
    }
    __syncthreads();
    {
      int e = tid;
      int bl2 = e >> 8, m = (e >> 7) & 1, pp = (e >> 4) & 7, oc2 = (e & 15) * 2;
      int w0 = bl2 * 4 + 2 * m;
      float s0 = bf2f(zpl[(w0*16 + 2*pp)*32 + oc2])     + bf2f(zpl[(w0*16 + 2*pp+1)*32 + oc2]) +
                 bf2f(zpl[((w0+1)*16 + 2*pp)*32 + oc2]) + bf2f(zpl[((w0+1)*16 + 2*pp+1)*32 + oc2]);
      float s1 = bf2f(zpl[(w0*16 + 2*pp)*32 + oc2+1])     + bf2f(zpl[(w0*16 + 2*pp+1)*32 + oc2+1]) +
                 bf2f(zpl[((w0+1)*16 + 2*pp)*32 + oc2+1]) + bf2f(zpl[((w0+1)*16 + 2*pp+1)*32 + oc2+1]);
      unsigned int pk = (unsigned int)f2bf(0.25f * s0) | ((unsigned int)f2bf(0.25f * s1) << 16);
      *(unsigned int*)&z2bf[(size_t)t * 524288 +
          ((((b0 + bl2) * 8) + q * 2 + m) * 8 + pp) * 64 + ocg * 32 + oc2] = pk;
    }
  }
}

// ---------- conv3 (64->128) MFMA full-K, t-loop, state in regs -> z3t[t] ----------
// grid 512 = ocg(8: 16 oc) x bg(64: 2 imgs); 512 thr = 8 waves.
// LDS: wl 55296 (both ics resident) + img 34560 + zpl 4096 = 93952 B -> 1 block/CU.
__global__ __launch_bounds__(512) void k_conv3(const unsigned short* __restrict__ z2bf,
    const unsigned short* __restrict__ wpk, unsigned short* __restrict__ z3t)
{
  const int bid = blockIdx.x;
  const int ocg = bid & 7, bg = bid >> 3;
  const int b0 = bg * 2;
  const int tid = threadIdx.x;
  __shared__ __align__(16) unsigned short wl[27648];       // [ics2][sp3][9][g4][ocl16][j8]
  __shared__ __align__(16) unsigned short img[2][10][12][72];
  __shared__ __align__(16) unsigned short zpl[2048];       // [8 w][16 px][16 oc]
  {
    const uint4* wsrc = (const uint4*)(wpk + ocg * 27648);
    for (int i = tid; i < 3456; i += 512) ((uint4*)wl)[i] = wsrc[i];
  }
  const int w = tid >> 6, l = tid & 63;
  const int bl = w >> 2, q3 = w & 3;
  const int lg = l >> 4, ll = l & 15;
  const int ry = ll >> 3, xi = ll & 7;
  float vst[4], ist[4];
#pragma unroll
  for (int r = 0; r < 4; ++r) { vst[r] = 0.f; ist[r] = 0.f; }

  for (int t = 0; t < 16; ++t) {
    __syncthreads();                      // prior-t img/zpl readers done
    if (tid < 240) {
      int ibl = tid / 120, rr = tid % 120;
      int row = rr / 12, col = rr % 12;
      int gy = row - 1, gx = col - 1;
      uint4* d = (uint4*)&img[ibl][row][col][0];
      uint4 zz = {0, 0, 0, 0};
      if (gy >= 0 && gy < 8 && gx >= 0 && gx < 8) {
        const uint4* s = (const uint4*)(z2bf + (size_t)t * 524288 +
                                        (((b0 + ibl) * 8 + gy) * 8 + gx) * 64);
#pragma unroll
        for (int u = 0; u < 8; ++u) d[u] = s[u];
        d[8] = zz;
      } else {
#pragma unroll
        for (int u = 0; u < 9; ++u) d[u] = zz;
      }
    }
    __syncthreads();
    f32x4 acc = {};
    for (int ics = 0; ics < 2; ++ics) {
      for (int sp = 0; sp < 3; ++sp) {
        for (int s9 = 0; s9 < 9; ++s9) {
          const int dy = s9 / 3, dx = s9 % 3;
          bf16x8 a = *(const bf16x8*)&img[bl][2 * q3 + ry + dy][xi + dx][ics * 32 + 8 * lg];
          bf16x8 bw = *(const bf16x8*)&wl[(((ics * 3 + sp) * 9 + s9) * 4 + lg) * 128 + ll * 8];
          acc = mfma16(a, bw, acc);
        }
      }
    }
#pragma unroll
    for (int r = 0; r < 4; ++r) {
      int px = 4 * lg + r;
      float z = lif1(acc[r], 0.1f, vst[r], ist[r]);
      zpl[(w * 16 + px) * 16 + ll] = f2bf(z);
    }
    __syncthreads();
    {
      int e = tid;
      int ocl = e & 15, st = (e >> 4) & 15, bl2 = e >> 8;
      int py = st >> 2, ppx = st & 3;
      int w0 = bl2 * 4 + py;
      float zsum = bf2f(zpl[(w0*16 + 2*ppx)*16 + ocl])   + bf2f(zpl[(w0*16 + 2*ppx+1)*16 + ocl]) +
                   bf2f(zpl[(w0*16 + 8+2*ppx)*16 + ocl]) + bf2f(zpl[(w0*16 + 8+2*ppx+1)*16 + ocl]);
      z3t[(size_t)t * 262144 + (b0 + bl2) * 2048 + (ocg * 16 + ocl) * 16 + py * 4 + ppx]
          = f2bf(0.25f * zsum);
    }
  }
}

// ---------- fc1 (2048->1024) MFMA, K-split 8, t-loop (stateless) -> P1[t][kb][b][n] ----------
// grid 512 = kb8 x nb32 x bb2; 512 thr = 8 waves = bt4 x nt2.
// LDS: wl3 49152 + slab 32768 = 81920 B.
__global__ __launch_bounds__(512) void k_fc1(const unsigned short* __restrict__ z3t,
    const float* __restrict__ wf1, float* __restrict__ P1)
{
  const int bid = blockIdx.x;
  const int kb = bid & 7, nb = (bid >> 3) & 31, bb = bid >> 8;
  const int tid = threadIdx.x;
  __shared__ __align__(16) unsigned short slab[16384];  // [64 b][32 grp^swz][8]
  __shared__ __align__(16) unsigned short wl3[24576];   // [sp3][ks8][g4][n32][j8]
  for (int i = tid; i < 24576; i += 512) {
    int sp = i >> 13, idx = i & 8191;
    int n = idx >> 8, k = idx & 255;
    float wv = wf1[(size_t)(nb * 32 + n) * 2048 + kb * 256 + k];
    int ks = k >> 5, g = (k >> 3) & 3, j = k & 7;
    wl3[sp * 8192 + ((ks * 4 + g) * 32 + n) * 8 + j] = split3(wv, sp);
  }
  const int w = tid >> 6, l = tid & 63;
  const int lg = l >> 4, ll = l & 15;
  const int bt = w >> 1, nt = w & 1;
  const int arow = bt * 16 + ll;
  const int bo = bb * 64 + bt * 16;

  for (int t = 0; t < 16; ++t) {
    __syncthreads();                      // prior-t slab readers done (covers wl3 stage at t=0)
    for (int gidx = tid; gidx < 2048; gidx += 512) {
      int row = gidx >> 5, gc = gidx & 31;
      const uint4* s = (const uint4*)(z3t + (size_t)t * 262144 +
                                      ((bb * 64 + row) * 2048 + kb * 256 + gc * 8));
      ((uint4*)slab)[row * 32 + (gc ^ (row & 7))] = *s;
    }
    __syncthreads();
    f32x4 acc = {};
#pragma unroll
    for (int sp = 0; sp < 3; ++sp) {
#pragma unroll
      for (int ks = 0; ks < 8; ++ks) {
        bf16x8 a = *(const bf16x8*)&slab[(arow * 32 + ((ks * 4 + lg) ^ (arow & 7))) * 8];
        bf16x8 bw = *(const bf16x8*)&wl3[sp * 8192 + ((ks * 4 + lg) * 32 + nt * 16 + ll) * 8];
        acc = mfma16(a, bw, acc);
      }
    }
    float* Pt = P1 + (size_t)t * 1048576 + (size_t)kb * 131072;
#pragma unroll
    for (int r = 0; r < 4; ++r)
      Pt[(bo + 4 * lg + r) * 1024 + nb * 32 + nt * 16 + ll] = acc[r];
  }
}

// ---------- fc1 reduce + LIF(0.1), t-loop, state in regs -> z4bf[t][b][n] ----------
// grid 512 x 256: one thread per (b,n) site
__global__ __launch_bounds__(256) void k_fc1b(const float* __restrict__ P1,
    unsigned short* __restrict__ z4bf)
{
  const int site = blockIdx.x * 256 + threadIdx.x;   // 131072 = b*1024+n
  float v = 0.f, ii = 0.f;
  for (int t = 0; t < 16; ++t) {
    const float* p = P1 + (size_t)t * 1048576 + site;
    float a = 0.f;
#pragma unroll
    for (int kb = 0; kb < 8; ++kb) a += p[(size_t)kb * 131072];
    float z = lif1(a, 0.1f, v, ii);
    z4bf[(size_t)t * 131072 + site] = f2bf(z);
  }
}

// ---------- out layer (1024->10) + LI + running max, t-loop, state in regs ----------
// grid 32 x 256: wave per batch row (4 b per block)
__global__ __launch_bounds__(256) void k_out(const unsigned short* __restrict__ z4bf,
    const float* __restrict__ wo, float* __restrict__ out)
{
  const int w = threadIdx.x >> 6, l = threadIdx.x & 63;
  const int b = blockIdx.x * 4 + w;
  float vo[10], io[10], om[10];
#pragma unroll
  for (int o = 0; o < 10; ++o) { vo[o] = 0.f; io[o] = 0.f; om[o] = 0.f; }
  for (int t = 0; t < 16; ++t) {
    float dot[10];
#pragma unroll
    for (int o = 0; o < 10; ++o) dot[o] = 0.f;
    for (int c = 0; c < 16; ++c) {
      const int n = c * 64 + l;
      float z = bf2f(z4bf[(size_t)t * 131072 + b * 1024 + n]);
#pragma unroll
      for (int o = 0; o < 10; ++o) dot[o] = fmaf(z, wo[o * 1024 + n], dot[o]);
    }
#pragma unroll
    for (int o = 0; o < 10; ++o)
#pragma unroll
      for (int d = 32; d > 0; d >>= 1) dot[o] += __shfl_down(dot[o], d);
    if (l == 0) {
#pragma unroll
      for (int o = 0; o < 10; ++o) {
        float vn = fmaf(0.1f, io[o] - vo[o], vo[o]);
        io[o] = fmaf(0.8f, io[o], dot[o]);
        vo[o] = vn;
        om[o] = (t == 0) ? vn : fmaxf(om[o], vn);
      }
    }
  }
  if (l == 0) {
#pragma unroll
    for (int o = 0; o < 10; ++o) out[b * 10 + o] = om[o];
  }
}

extern "C" void kernel_launch(void* const* d_in, const int* in_sizes, int n_in,
                              void* d_out, int out_size, void* d_ws, size_t ws_size,
                              hipStream_t stream)
{
  const float* x   = (const float*)d_in[0];   // (16,128,3,32,32)
  const float* wc1 = (const float*)d_in[1];   // (32,3,3,3)
  const float* wc2 = (const float*)d_in[2];   // (64,32,3,3)
  const float* wc3 = (const float*)d_in[3];   // (128,64,3,3)
  const float* wf1 = (const float*)d_in[4];   // (1024,2048)
  const float* wo  = (const float*)d_in[5];   // (10,1024)
  float* out = (float*)d_out;                 // (128,10)
  char* ws = (char*)d_ws;

  // byte offsets (all activations carry a [t] dimension; no state arrays at all)
  unsigned short* z1bf = (unsigned short*)(ws + 0);          // [16][128,16,16,32] = 33.5 MB
  unsigned short* z2bf = (unsigned short*)(ws + 33554432);   // [16][128,8,8,64]  = 16.8 MB
  unsigned short* z3t  = (unsigned short*)(ws + 50331648);   // [16][128,2048]    = 8.4 MB
  unsigned short* z4bf = (unsigned short*)(ws + 58720256);   // [16][128,1024]    = 4.2 MB
  float* P1            = (float*)(ws + 62914560);            // [16][8][131072]   = 67.1 MB
  unsigned short* wc2pk = (unsigned short*)(ws + 130023424); // 55296 sh
  unsigned short* wc3pk = (unsigned short*)(ws + 130134016); // 442368 sh
  // end 131,018,752 bytes (ws_size = 256 MiB)

  k_pack2<<<216, 256, 0, stream>>>(wc2, wc2pk);
  k_pack3<<<1728, 256, 0, stream>>>(wc3, wc3pk);

  k_conv1<<<512, 256, 0, stream>>>(x, wc1, z1bf);
  k_conv2<<<512, 512, 0, stream>>>(z1bf, wc2pk, z2bf);
  k_conv3<<<512, 512, 0, stream>>>(z2bf, wc3pk, z3t);
  k_fc1 <<<512, 512, 0, stream>>>(z3t, wf1, P1);
  k_fc1b<<<512, 256, 0, stream>>>(P1, z4bf);
  k_out <<<32, 256, 0, stream>>>(z4bf, wo, out);
}